// Round 17
// baseline (1813.232 us; speedup 1.0000x reference)
//
#include <hip/hip_runtime.h>
#include <hip/hip_cooperative_groups.h>

namespace cg = cooperative_groups;

#define B_    8
#define V_    50000
#define KNB   9
#define CIN_  64
#define COUT_ 128
#define VOUT_ 12500
#define NNZ_  37500
#define KTOT  576      // KNB*CIN_
#define NWG   3125     // fallback worst-case grid (>= 8*ceil(37500/128)=2344)
#define GRID_ 512      // cooperative grid: 2 blocks/CU guaranteed (51.4KB LDS, 256-reg budget)

typedef short bf16x8 __attribute__((ext_vector_type(8)));
typedef float f32x4  __attribute__((ext_vector_type(4)));

#define AS1 __attribute__((address_space(1)))
#define AS3 __attribute__((address_space(3)))

__device__ __forceinline__ unsigned short f2bf(float f) {
  unsigned u = __float_as_uint(f);
  u += 0x7fffu + ((u >> 16) & 1u);          // RNE
  return (unsigned short)(u >> 16);
}
__device__ __forceinline__ unsigned pack2(float lo, float hi) {
  return (unsigned)f2bf(lo) | ((unsigned)f2bf(hi) << 16);
}
__device__ __forceinline__ float bf2f(unsigned short u) {
  return __uint_as_float((unsigned)u << 16);
}
__device__ __forceinline__ void gld_lds16(const void* g, void* l) {
  __builtin_amdgcn_global_load_lds((const AS1 unsigned*)g, (AS3 unsigned*)l, 16, 0, 0);
}

struct GemmSM { char A[3][16384]; unsigned short spc[1152]; };  // 51,456 B

// ---------------- shared device pieces ----------------

__device__ __forceinline__ void wfrag_one(const float* __restrict__ w,
                                          unsigned short* __restrict__ wfr, int i) {
  // W -> MFMA-fragment-major: chunk i holds, for lane=i&63, n=(i>>6)&3,
  // wc=(i>>8)&1, ks=(i>>9)&1, t=i>>10:
  //   W[col=wc*64+n*16+(lane&15)][k=t*64+ks*32+(lane>>4)*8 .. +8]
  int lane = i & 63, n = (i >> 6) & 3, wc = (i >> 8) & 1, ks = (i >> 9) & 1, t = i >> 10;
  int col = wc * 64 + n * 16 + (lane & 15);
  int k0 = t * 64 + ks * 32 + (lane >> 4) * 8;
  const float* src = w + (size_t)col * KTOT + k0;
  float4 f0 = reinterpret_cast<const float4*>(src)[0];
  float4 f1 = reinterpret_cast<const float4*>(src)[1];
  uint4 o;
  o.x = pack2(f0.x, f0.y);
  o.y = pack2(f0.z, f0.w);
  o.z = pack2(f1.x, f1.y);
  o.w = pack2(f1.z, f1.w);
  reinterpret_cast<uint4*>(wfr)[i] = o;
}

__device__ __forceinline__ void bucket_one(const int* __restrict__ dr,
                                           const int* __restrict__ dc,
                                           const float* __restrict__ dd,
                                           int* __restrict__ cursor,
                                           int* __restrict__ used,
                                           int* __restrict__ Ucnt,
                                           int2* __restrict__ elist,
                                           int* __restrict__ rmap,
                                           int* __restrict__ cidx, int e) {
  int r = dr[e], c = dc[e];
  int slot = atomicAdd(&cursor[r], 1);
  if (slot < 32) elist[r * 32 + slot] = make_int2(c, __float_as_int(dd[e]));
  if (atomicExch(&used[c], 1) == 0) {
    int u = atomicAdd(Ucnt, 1);
    rmap[u] = c;
    cidx[c] = u;
  }
}

__device__ __forceinline__ void convert_slice(const float* __restrict__ x,
                                              unsigned short* __restrict__ xbf,
                                              int b, int widx, int nw, int tid) {
  const int nq = V_ * CIN_ / 4;                       // 800000 quads per slice
  const float4* src = reinterpret_cast<const float4*>(x) + (size_t)b * nq;
  ushort4* dst = reinterpret_cast<ushort4*>(xbf) + (size_t)b * nq;
  for (int q = widx * 256 + tid; q < nq; q += nw * 256) {
    float4 f = src[q];
    ushort4 o;
    o.x = f2bf(f.x); o.y = f2bf(f.y); o.z = f2bf(f.z); o.w = f2bf(f.w);
    dst[q] = o;
  }
}

// One 128x128 tile of batch b (rows m0..m0+127 of the compacted per-batch index).
// Inner loop = R12/R15 pipeline verbatim: A 3-buf gld_lds 2-deep, B double-banked
// regs, raw s_barrier/iter, hand vmcnt {4,12,8}.
__device__ __forceinline__ void gemm_tile(
    GemmSM* sm, int b, int tb, int U,
    const unsigned short* __restrict__ xbf, const unsigned short* __restrict__ wfr,
    const float* __restrict__ bias, const int* __restrict__ sp,
    const int* __restrict__ rmap, unsigned short* __restrict__ hbf)
{
  const int tid  = threadIdx.x;
  const int m0   = tb * 128;
  const int wave = tid >> 6;
  const int lane = tid & 63;

  for (int i = tid; i < 128 * KNB; i += 256) {
    int row = i / KNB, j = i - row * KNB;
    int u = m0 + row; if (u >= U) u = U - 1;
    sm->spc[i] = (unsigned short)sp[rmap[u] * KNB + j];
  }

  const int rrow  = tid >> 3;
  const int chunkoff = (((tid & 7) ^ (rrow & 7)) << 4);
  const unsigned bboff = (unsigned)b * (V_ * CIN_ * 2);
  int sbase[4], ldso[4];
  #pragma unroll
  for (int r = 0; r < 4; ++r) {
    sbase[r] = (r * 32 + rrow) * KNB;
    ldso[r]  = (r * 32 + wave * 8) * 128;
  }

  const int wr = wave >> 1, wc = wave & 1;
  const int lr = lane & 15, lg = lane >> 4;
  const bf16x8* wbase = (const bf16x8*)wfr + wc * 256 + lane;

  f32x4 acc[4][4];
  #pragma unroll
  for (int i = 0; i < 4; ++i)
    #pragma unroll
    for (int j = 0; j < 4; ++j)
      acc[i][j] = (f32x4){0.f, 0.f, 0.f, 0.f};

  auto stageA = [&](int bi, int t) {
    char* Ab = sm->A[bi];
    #pragma unroll
    for (int r = 0; r < 4; ++r) {
      unsigned idx = sm->spc[sbase[r] + t];
      unsigned off = bboff + idx * 128u + (unsigned)chunkoff;
      gld_lds16((const char*)xbf + off, Ab + ldso[r]);
    }
  };
  bf16x8 b0[2][4], b1[2][4];
  auto loadB = [&](bf16x8 (&bk)[2][4], int t) {
    #pragma unroll
    for (int ks = 0; ks < 2; ++ks)
      #pragma unroll
      for (int n = 0; n < 4; ++n)
        bk[ks][n] = wbase[(t * 2 + ks) * 512 + n * 64];
  };

  __syncthreads();          // spc visible
  loadB(b0, 0);
  stageA(0, 0);
  stageA(1, 1);

#define GITER(T, BC, BN)                                                        \
  do {                                                                          \
    asm volatile("s_waitcnt vmcnt(%0)"                                          \
                 :: "i"((T) == 0 ? 4 : ((T) <= 7 ? 12 : 8)) : "memory");        \
    __builtin_amdgcn_sched_barrier(0);                                          \
    __builtin_amdgcn_s_barrier();                                               \
    if ((T) + 1 < KNB) loadB(BN, (T) + 1);                                      \
    __builtin_amdgcn_sched_barrier(0);                                          \
    if ((T) + 2 < KNB) stageA(((T) + 2) % 3, (T) + 2);                          \
    __builtin_amdgcn_sched_barrier(0);                                          \
    {                                                                           \
      const char* Ab = sm->A[(T) % 3];                                          \
      _Pragma("unroll")                                                         \
      for (int ks = 0; ks < 2; ++ks) {                                          \
        const int kb = ks * 64 + lg * 16;                                       \
        bf16x8 af[4];                                                           \
        _Pragma("unroll")                                                       \
        for (int m = 0; m < 4; ++m) {                                           \
          int row = wr * 64 + m * 16 + lr;                                      \
          af[m] = *reinterpret_cast<const bf16x8*>(                             \
              Ab + row * 128 + (kb ^ ((row & 7) << 4)));                        \
        }                                                                       \
        __builtin_amdgcn_s_setprio(1);                                          \
        _Pragma("unroll")                                                       \
        for (int m = 0; m < 4; ++m)                                             \
          _Pragma("unroll")                                                     \
          for (int n = 0; n < 4; ++n)                                           \
            acc[m][n] = __builtin_amdgcn_mfma_f32_16x16x32_bf16(                \
                af[m], BC[ks][n], acc[m][n], 0, 0, 0);                          \
        __builtin_amdgcn_s_setprio(0);                                          \
      }                                                                         \
    }                                                                           \
    asm volatile("s_waitcnt lgkmcnt(0)" ::: "memory");                          \
    __builtin_amdgcn_sched_barrier(0);                                          \
  } while (0)

  GITER(0, b0, b1);
  GITER(1, b1, b0);
  GITER(2, b0, b1);
  GITER(3, b1, b0);
  GITER(4, b0, b1);
  GITER(5, b1, b0);
  GITER(6, b0, b1);
  GITER(7, b1, b0);
  GITER(8, b0, b1);
#undef GITER

  __syncthreads();
  char* hsb = (char*)sm;
  #pragma unroll
  for (int n = 0; n < 4; ++n) {
    const int c = wc * 64 + n * 16 + lr;
    const float bv = bias[c];
    #pragma unroll
    for (int m = 0; m < 4; ++m) {
      const int row0 = wr * 64 + m * 16 + lg * 4;
      #pragma unroll
      for (int j = 0; j < 4; ++j) {
        const int row = row0 + j;
        float vv = acc[m][n][j] + bv;
        vv = vv > 0.f ? vv : (__expf(vv) - 1.f);
        *reinterpret_cast<unsigned short*>(
            hsb + row * 256 + ((c * 2) ^ ((row & 7) << 4))) = f2bf(vv);
      }
    }
  }
  __syncthreads();
  const int r2 = tid >> 1, hf = tid & 1;
  if (m0 + r2 < U) {
    uint4* drow = reinterpret_cast<uint4*>(
        hbf + ((size_t)b * U + m0 + r2) * COUT_ + hf * 64);
    #pragma unroll
    for (int u = 0; u < 8; ++u) {
      int cb = hf * 128 + u * 16;
      drow[u] = *reinterpret_cast<const uint4*>(hsb + r2 * 256 + (cb ^ ((r2 & 7) << 4)));
    }
  }
}

__device__ __forceinline__ void pool_row_body(const unsigned short* __restrict__ hbf,
                                              const int* __restrict__ cursor,
                                              const int2* __restrict__ elist,
                                              const int* __restrict__ cidx,
                                              int U, int row,
                                              float* __restrict__ out) {
  const int bg = threadIdx.x >> 5;
  const int lc = threadIdx.x & 31;
  int cnt = cursor[row];
  cnt = cnt < 32 ? cnt : 32;
  const unsigned short* hb = hbf + (size_t)bg * U * COUT_ + lc * 4;
  float4 acc = {0.f, 0.f, 0.f, 0.f};
  for (int e = 0; e < cnt; ++e) {
    int2 en = elist[row * 32 + e];
    float d = __int_as_float(en.y);
    int u = cidx[en.x];
    ushort4 v = *reinterpret_cast<const ushort4*>(hb + (size_t)u * COUT_);
    acc.x += d * bf2f(v.x);
    acc.y += d * bf2f(v.y);
    acc.z += d * bf2f(v.z);
    acc.w += d * bf2f(v.w);
  }
  *reinterpret_cast<float4*>(out + ((size_t)bg * VOUT_ + row) * COUT_ + lc * 4) = acc;
}

// ---------------- cooperative fused kernel ----------------
// R17 coherence hardening (G16): release fence BEFORE each grid.sync AND acquire
// fence AFTER it (reader-side L1/L2 invalidation); Ucnt read with agent-scope
// atomic acquire. Phase b: blocks<ntb gemm batch b | others convert slice b+1.
__global__ __launch_bounds__(256, 2) void fused_all(
    const float* __restrict__ x, const float* __restrict__ w,
    const float* __restrict__ bias, const int* __restrict__ sp,
    const int* __restrict__ dr, const int* __restrict__ dc,
    const float* __restrict__ dd,
    unsigned short* __restrict__ wfr, unsigned short* __restrict__ xbf,
    unsigned short* __restrict__ hbf,
    int* __restrict__ cursor, int* __restrict__ used, int* __restrict__ Ucnt,
    int2* __restrict__ elist, int* __restrict__ rmap, int* __restrict__ cidx,
    float* __restrict__ out)
{
  __shared__ GemmSM smv;
  cg::grid_group grid = cg::this_grid();
  const int bid = blockIdx.x;
  const int tid = threadIdx.x;

  // ---- prologue: 36 W-frag blocks + 147 bucket blocks + 329 convert blocks
  if (bid < 36) {
    wfrag_one(w, wfr, bid * 256 + tid);
  } else if (bid < 183) {
    int e = (bid - 36) * 256 + tid;
    if (e < NNZ_) bucket_one(dr, dc, dd, cursor, used, Ucnt, elist, rmap, cidx, e);
  } else {
    convert_slice(x, xbf, 0, bid - 183, GRID_ - 183, tid);
  }
  __threadfence();          // release
  grid.sync();
  __threadfence();          // acquire: invalidate stale L1/L2 before reading

  const int U = __hip_atomic_load(Ucnt, __ATOMIC_ACQUIRE, __HIP_MEMORY_SCOPE_AGENT);
  const int ntb = (U + 127) >> 7;        // tiles per batch (<=293)

  for (int b = 0; b < B_; ++b) {
    if (bid < ntb) {
      gemm_tile(&smv, b, bid, U, xbf, wfr, bias, sp, rmap, hbf);
    } else if (b + 1 < B_) {
      convert_slice(x, xbf, b + 1, bid - ntb, GRID_ - ntb, tid);
    }
    __threadfence();        // release
    grid.sync();
    __threadfence();        // acquire
  }

  // ---- pool phase
  for (int row = bid; row < VOUT_; row += GRID_) {
    pool_row_body(hbf, cursor, elist, cidx, U, row, out);
  }
}

// ---------------- fallback path (R15-equivalent, tile-count bug FIXED) ----------------

#define PREP_WBLK 36
#define PREP_FBLK 147
#define PREP_XBLK 2048
__global__ __launch_bounds__(256) void prep(const float* __restrict__ w,
                                            unsigned short* __restrict__ wfr,
                                            const float* __restrict__ x,
                                            unsigned short* __restrict__ xbf,
                                            const int* __restrict__ dr,
                                            const int* __restrict__ dc,
                                            const float* __restrict__ dd,
                                            int* __restrict__ cursor,
                                            int* __restrict__ used,
                                            int* __restrict__ Ucnt,
                                            int2* __restrict__ elist,
                                            int* __restrict__ rmap,
                                            int* __restrict__ cidx) {
  const int bid = blockIdx.x;
  if (bid < PREP_WBLK) {
    wfrag_one(w, wfr, bid * 256 + threadIdx.x);
  } else if (bid < PREP_WBLK + PREP_FBLK) {
    int e = (bid - PREP_WBLK) * 256 + threadIdx.x;
    if (e < NNZ_) bucket_one(dr, dc, dd, cursor, used, Ucnt, elist, rmap, cidx, e);
  } else {
    const int nq = B_ * V_ * CIN_ / 4;
    for (int q = (bid - PREP_WBLK - PREP_FBLK) * 256 + threadIdx.x; q < nq;
         q += PREP_XBLK * 256) {
      float4 f = reinterpret_cast<const float4*>(x)[q];
      ushort4 o;
      o.x = f2bf(f.x); o.y = f2bf(f.y); o.z = f2bf(f.z); o.w = f2bf(f.w);
      reinterpret_cast<ushort4*>(xbf)[q] = o;
    }
  }
}

__global__ __launch_bounds__(256, 3) void spiral_gemm(
    const unsigned short* __restrict__ xbf, const unsigned short* __restrict__ wfr,
    const float* __restrict__ bias, const int* __restrict__ sp,
    const int* __restrict__ rmap, const int* __restrict__ Ucnt,
    unsigned short* __restrict__ hbf)
{
  __shared__ GemmSM smv;
  const int U   = *Ucnt;
  const int ntb = (U + 127) >> 7;
  const int ntt = 8 * ntb;               // R17 FIX: per-batch padded tile count
  if ((int)blockIdx.x >= ntt) return;
  // bijective XCD swizzle over ntt
  const int q_ = ntt >> 3, r_ = ntt & 7;
  const int xcd = blockIdx.x & 7, pos = blockIdx.x >> 3;
  const int nbid = (xcd < r_) ? xcd * (q_ + 1) + pos
                              : r_ * (q_ + 1) + (xcd - r_) * q_ + pos;
  const int b  = nbid / ntb;
  const int tb = nbid - b * ntb;
  gemm_tile(&smv, b, tb, U, xbf, wfr, bias, sp, rmap, hbf);
}

__global__ __launch_bounds__(256) void pool_rows(const unsigned short* __restrict__ hbf,
                                                 const int* __restrict__ cursor,
                                                 const int2* __restrict__ elist,
                                                 const int* __restrict__ cidx,
                                                 const int* __restrict__ Ucnt,
                                                 float* __restrict__ out) {
  pool_row_body(hbf, cursor, elist, cidx, *Ucnt, blockIdx.x, out);
}

extern "C" void kernel_launch(void* const* d_in, const int* in_sizes, int n_in,
                              void* d_out, int out_size, void* d_ws, size_t ws_size,
                              hipStream_t stream) {
  const float* x    = (const float*)d_in[0];
  const float* w    = (const float*)d_in[1];
  const float* bias = (const float*)d_in[2];
  const int*   sp   = (const int*)d_in[3];
  const int*   dr   = (const int*)d_in[4];
  const int*   dc   = (const int*)d_in[5];
  const float* dd   = (const float*)d_in[6];
  float* out = (float*)d_out;

  char* ws = (char*)d_ws;
  unsigned short* wfr = (unsigned short*)ws;        // 147456 B (frag-major W)
  unsigned short* xbf = (unsigned short*)(ws + 147456);     // 51200000 B
  unsigned short* hbf = (unsigned short*)(ws + 51347456);   // 102400000 B worst case
  int*  cursor  = (int*) (ws + 153747456);          // 50000 B (memset with used+Ucnt)
  int*  used    = (int*) (ws + 153797456);          // 200000 B
  int*  Ucnt    = (int*) (ws + 153997456);          // 16 B
  int2* elist   = (int2*)(ws + 153997472);          // 3200000 B
  int*  rmap    = (int*) (ws + 157197472);          // 200000 B
  int*  cidx    = (int*) (ws + 157397472);          // 200000 B

  (void)hipMemsetAsync(cursor, 0, 250016, stream);  // cursor + used + Ucnt

  void* args[] = { (void*)&x, (void*)&w, (void*)&bias, (void*)&sp,
                   (void*)&dr, (void*)&dc, (void*)&dd,
                   (void*)&wfr, (void*)&xbf, (void*)&hbf,
                   (void*)&cursor, (void*)&used, (void*)&Ucnt,
                   (void*)&elist, (void*)&rmap, (void*)&cidx, (void*)&out };
  hipError_t err = hipLaunchCooperativeKernel((const void*)fused_all,
                                              dim3(GRID_), dim3(256),
                                              args, 0, stream);
  if (err != hipSuccess) {
    // Fallback: three-kernel path (R15-equivalent; tile-count bug fixed).
    prep<<<PREP_WBLK + PREP_FBLK + PREP_XBLK, 256, 0, stream>>>(
        w, wfr, x, xbf, dr, dc, dd, cursor, used, Ucnt, elist, rmap, cidx);
    spiral_gemm<<<NWG, 256, 0, stream>>>(xbf, wfr, bias, sp, rmap, Ucnt, hbf);
    pool_rows<<<VOUT_, 256, 0, stream>>>(hbf, cursor, elist, cidx, Ucnt, out);
  }
}

// Round 18
// 123.119 us; speedup vs baseline: 14.7275x; 14.7275x over previous
//
#include <hip/hip_runtime.h>

#define B_    8
#define V_    50000
#define KNB   9
#define CIN_  64
#define COUT_ 128
#define VOUT_ 12500
#define NNZ_  37500
#define KTOT  576      // KNB*CIN_
#define NWG   3125     // worst-case grid (>= 8*ceil(37500/128)=2344)

typedef short bf16x8 __attribute__((ext_vector_type(8)));
typedef float f32x4  __attribute__((ext_vector_type(4)));

#define AS1 __attribute__((address_space(1)))
#define AS3 __attribute__((address_space(3)))

__device__ __forceinline__ unsigned short f2bf(float f) {
  unsigned u = __float_as_uint(f);
  u += 0x7fffu + ((u >> 16) & 1u);          // RNE
  return (unsigned short)(u >> 16);
}
__device__ __forceinline__ unsigned pack2(float lo, float hi) {
  return (unsigned)f2bf(lo) | ((unsigned)f2bf(hi) << 16);
}
__device__ __forceinline__ float bf2f(unsigned short u) {
  return __uint_as_float((unsigned)u << 16);
}
__device__ __forceinline__ void gld_lds16(const void* g, void* l) {
  __builtin_amdgcn_global_load_lds((const AS1 unsigned*)g, (AS3 unsigned*)l, 16, 0, 0);
}

struct GemmSM { char A[3][16384]; unsigned short spc[1152]; };  // 51,456 B

// ---------------- device pieces ----------------

__device__ __forceinline__ void wfrag_one(const float* __restrict__ w,
                                          unsigned short* __restrict__ wfr, int i) {
  // W -> MFMA-fragment-major: chunk i holds, for lane=i&63, n=(i>>6)&3,
  // wc=(i>>8)&1, ks=(i>>9)&1, t=i>>10:
  //   W[col=wc*64+n*16+(lane&15)][k=t*64+ks*32+(lane>>4)*8 .. +8]
  int lane = i & 63, n = (i >> 6) & 3, wc = (i >> 8) & 1, ks = (i >> 9) & 1, t = i >> 10;
  int col = wc * 64 + n * 16 + (lane & 15);
  int k0 = t * 64 + ks * 32 + (lane >> 4) * 8;
  const float* src = w + (size_t)col * KTOT + k0;
  float4 f0 = reinterpret_cast<const float4*>(src)[0];
  float4 f1 = reinterpret_cast<const float4*>(src)[1];
  uint4 o;
  o.x = pack2(f0.x, f0.y);
  o.y = pack2(f0.z, f0.w);
  o.z = pack2(f1.x, f1.y);
  o.w = pack2(f1.z, f1.w);
  reinterpret_cast<uint4*>(wfr)[i] = o;
}

__device__ __forceinline__ void bucket_one(const int* __restrict__ dr,
                                           const int* __restrict__ dc,
                                           const float* __restrict__ dd,
                                           int* __restrict__ cursor,
                                           int* __restrict__ used,
                                           int* __restrict__ Ucnt,
                                           int2* __restrict__ elist,
                                           int* __restrict__ rmap,
                                           int* __restrict__ cidx, int e) {
  int r = dr[e], c = dc[e];
  int slot = atomicAdd(&cursor[r], 1);
  if (slot < 32) elist[r * 32 + slot] = make_int2(c, __float_as_int(dd[e]));
  if (atomicExch(&used[c], 1) == 0) {
    int u = atomicAdd(Ucnt, 1);
    rmap[u] = c;
    cidx[c] = u;
  }
}

// One 128x128 tile of batch b (rows m0..m0+127 of the compacted per-batch index).
// R12/R15 pipeline verbatim: A 3-buf gld_lds 2-deep, B double-banked regs,
// raw s_barrier per iter, hand vmcnt {4,12,8}.
__device__ __forceinline__ void gemm_tile(
    GemmSM* sm, int b, int tb, int U,
    const unsigned short* __restrict__ xbf, const unsigned short* __restrict__ wfr,
    const float* __restrict__ bias, const int* __restrict__ sp,
    const int* __restrict__ rmap, unsigned short* __restrict__ hbf)
{
  const int tid  = threadIdx.x;
  const int m0   = tb * 128;
  const int wave = tid >> 6;
  const int lane = tid & 63;

  for (int i = tid; i < 128 * KNB; i += 256) {
    int row = i / KNB, j = i - row * KNB;
    int u = m0 + row; if (u >= U) u = U - 1;
    sm->spc[i] = (unsigned short)sp[rmap[u] * KNB + j];
  }

  const int rrow  = tid >> 3;
  const int chunkoff = (((tid & 7) ^ (rrow & 7)) << 4);
  const unsigned bboff = (unsigned)b * (V_ * CIN_ * 2);
  int sbase[4], ldso[4];
  #pragma unroll
  for (int r = 0; r < 4; ++r) {
    sbase[r] = (r * 32 + rrow) * KNB;
    ldso[r]  = (r * 32 + wave * 8) * 128;
  }

  const int wr = wave >> 1, wc = wave & 1;
  const int lr = lane & 15, lg = lane >> 4;
  const bf16x8* wbase = (const bf16x8*)wfr + wc * 256 + lane;

  f32x4 acc[4][4];
  #pragma unroll
  for (int i = 0; i < 4; ++i)
    #pragma unroll
    for (int j = 0; j < 4; ++j)
      acc[i][j] = (f32x4){0.f, 0.f, 0.f, 0.f};

  auto stageA = [&](int bi, int t) {
    char* Ab = sm->A[bi];
    #pragma unroll
    for (int r = 0; r < 4; ++r) {
      unsigned idx = sm->spc[sbase[r] + t];
      unsigned off = bboff + idx * 128u + (unsigned)chunkoff;
      gld_lds16((const char*)xbf + off, Ab + ldso[r]);
    }
  };
  bf16x8 b0[2][4], b1[2][4];
  auto loadB = [&](bf16x8 (&bk)[2][4], int t) {
    #pragma unroll
    for (int ks = 0; ks < 2; ++ks)
      #pragma unroll
      for (int n = 0; n < 4; ++n)
        bk[ks][n] = wbase[(t * 2 + ks) * 512 + n * 64];
  };

  __syncthreads();          // spc visible
  loadB(b0, 0);
  stageA(0, 0);
  stageA(1, 1);

#define GITER(T, BC, BN)                                                        \
  do {                                                                          \
    asm volatile("s_waitcnt vmcnt(%0)"                                          \
                 :: "i"((T) == 0 ? 4 : ((T) <= 7 ? 12 : 8)) : "memory");        \
    __builtin_amdgcn_sched_barrier(0);                                          \
    __builtin_amdgcn_s_barrier();                                               \
    if ((T) + 1 < KNB) loadB(BN, (T) + 1);                                      \
    __builtin_amdgcn_sched_barrier(0);                                          \
    if ((T) + 2 < KNB) stageA(((T) + 2) % 3, (T) + 2);                          \
    __builtin_amdgcn_sched_barrier(0);                                          \
    {                                                                           \
      const char* Ab = sm->A[(T) % 3];                                          \
      _Pragma("unroll")                                                         \
      for (int ks = 0; ks < 2; ++ks) {                                          \
        const int kb = ks * 64 + lg * 16;                                       \
        bf16x8 af[4];                                                           \
        _Pragma("unroll")                                                       \
        for (int m = 0; m < 4; ++m) {                                           \
          int row = wr * 64 + m * 16 + lr;                                      \
          af[m] = *reinterpret_cast<const bf16x8*>(                             \
              Ab + row * 128 + (kb ^ ((row & 7) << 4)));                        \
        }                                                                       \
        __builtin_amdgcn_s_setprio(1);                                          \
        _Pragma("unroll")                                                       \
        for (int m = 0; m < 4; ++m)                                             \
          _Pragma("unroll")                                                     \
          for (int n = 0; n < 4; ++n)                                           \
            acc[m][n] = __builtin_amdgcn_mfma_f32_16x16x32_bf16(                \
                af[m], BC[ks][n], acc[m][n], 0, 0, 0);                          \
        __builtin_amdgcn_s_setprio(0);                                          \
      }                                                                         \
    }                                                                           \
    asm volatile("s_waitcnt lgkmcnt(0)" ::: "memory");                          \
    __builtin_amdgcn_sched_barrier(0);                                          \
  } while (0)

  GITER(0, b0, b1);
  GITER(1, b1, b0);
  GITER(2, b0, b1);
  GITER(3, b1, b0);
  GITER(4, b0, b1);
  GITER(5, b1, b0);
  GITER(6, b0, b1);
  GITER(7, b1, b0);
  GITER(8, b0, b1);
#undef GITER

  __syncthreads();
  char* hsb = (char*)sm;
  #pragma unroll
  for (int n = 0; n < 4; ++n) {
    const int c = wc * 64 + n * 16 + lr;
    const float bv = bias[c];
    #pragma unroll
    for (int m = 0; m < 4; ++m) {
      const int row0 = wr * 64 + m * 16 + lg * 4;
      #pragma unroll
      for (int j = 0; j < 4; ++j) {
        const int row = row0 + j;
        float vv = acc[m][n][j] + bv;
        vv = vv > 0.f ? vv : (__expf(vv) - 1.f);
        *reinterpret_cast<unsigned short*>(
            hsb + row * 256 + ((c * 2) ^ ((row & 7) << 4))) = f2bf(vv);
      }
    }
  }
  __syncthreads();
  const int r2 = tid >> 1, hf = tid & 1;
  if (m0 + r2 < U) {
    uint4* drow = reinterpret_cast<uint4*>(
        hbf + ((size_t)b * U + m0 + r2) * COUT_ + hf * 64);
    #pragma unroll
    for (int u = 0; u < 8; ++u) {
      int cb = hf * 128 + u * 16;
      drow[u] = *reinterpret_cast<const uint4*>(hsb + r2 * 256 + (cb ^ ((r2 & 7) << 4)));
    }
  }
}

__device__ __forceinline__ void pool_row_body(const unsigned short* __restrict__ hbf,
                                              const int* __restrict__ cursor,
                                              const int2* __restrict__ elist,
                                              const int* __restrict__ cidx,
                                              int U, int row,
                                              float* __restrict__ out) {
  const int bg = threadIdx.x >> 5;
  const int lc = threadIdx.x & 31;
  int cnt = cursor[row];
  cnt = cnt < 32 ? cnt : 32;
  const unsigned short* hb = hbf + (size_t)bg * U * COUT_ + lc * 4;
  float4 acc = {0.f, 0.f, 0.f, 0.f};
  for (int e = 0; e < cnt; ++e) {
    int2 en = elist[row * 32 + e];
    float d = __int_as_float(en.y);
    int u = cidx[en.x];
    ushort4 v = *reinterpret_cast<const ushort4*>(hb + (size_t)u * COUT_);
    acc.x += d * bf2f(v.x);
    acc.y += d * bf2f(v.y);
    acc.z += d * bf2f(v.z);
    acc.w += d * bf2f(v.w);
  }
  *reinterpret_cast<float4*>(out + ((size_t)bg * VOUT_ + row) * COUT_ + lc * 4) = acc;
}

// ---------------- kernels (three-launch path; coop fusion removed after R17:
// 512-block grid.sync phase pipeline measured 15x SLOWER, 1907us) ----------------

#define PREP_WBLK 36
#define PREP_FBLK 147
#define PREP_XBLK 2048
__global__ __launch_bounds__(256) void prep(const float* __restrict__ w,
                                            unsigned short* __restrict__ wfr,
                                            const float* __restrict__ x,
                                            unsigned short* __restrict__ xbf,
                                            const int* __restrict__ dr,
                                            const int* __restrict__ dc,
                                            const float* __restrict__ dd,
                                            int* __restrict__ cursor,
                                            int* __restrict__ used,
                                            int* __restrict__ Ucnt,
                                            int2* __restrict__ elist,
                                            int* __restrict__ rmap,
                                            int* __restrict__ cidx) {
  const int bid = blockIdx.x;
  if (bid < PREP_WBLK) {
    wfrag_one(w, wfr, bid * 256 + threadIdx.x);
  } else if (bid < PREP_WBLK + PREP_FBLK) {
    int e = (bid - PREP_WBLK) * 256 + threadIdx.x;
    if (e < NNZ_) bucket_one(dr, dc, dd, cursor, used, Ucnt, elist, rmap, cidx, e);
  } else {
    const int nq = B_ * V_ * CIN_ / 4;
    for (int q = (bid - PREP_WBLK - PREP_FBLK) * 256 + threadIdx.x; q < nq;
         q += PREP_XBLK * 256) {
      float4 f = reinterpret_cast<const float4*>(x)[q];
      ushort4 o;
      o.x = f2bf(f.x); o.y = f2bf(f.y); o.z = f2bf(f.z); o.w = f2bf(f.w);
      reinterpret_cast<ushort4*>(xbf)[q] = o;
    }
  }
}

__global__ __launch_bounds__(256, 3) void spiral_gemm(
    const unsigned short* __restrict__ xbf, const unsigned short* __restrict__ wfr,
    const float* __restrict__ bias, const int* __restrict__ sp,
    const int* __restrict__ rmap, const int* __restrict__ Ucnt,
    unsigned short* __restrict__ hbf)
{
  __shared__ GemmSM smv;
  const int U   = *Ucnt;
  const int ntb = (U + 127) >> 7;
  const int ntt = 8 * ntb;               // per-batch padded tile count (R17 fix)
  if ((int)blockIdx.x >= ntt) return;
  // bijective XCD swizzle over ntt
  const int q_ = ntt >> 3, r_ = ntt & 7;
  const int xcd = blockIdx.x & 7, pos = blockIdx.x >> 3;
  const int nbid = (xcd < r_) ? xcd * (q_ + 1) + pos
                              : r_ * (q_ + 1) + (xcd - r_) * q_ + pos;
  const int b  = nbid / ntb;
  const int tb = nbid - b * ntb;
  gemm_tile(&smv, b, tb, U, xbf, wfr, bias, sp, rmap, hbf);
}

__global__ __launch_bounds__(256) void pool_rows(const unsigned short* __restrict__ hbf,
                                                 const int* __restrict__ cursor,
                                                 const int2* __restrict__ elist,
                                                 const int* __restrict__ cidx,
                                                 const int* __restrict__ Ucnt,
                                                 float* __restrict__ out) {
  pool_row_body(hbf, cursor, elist, cidx, *Ucnt, blockIdx.x, out);
}

extern "C" void kernel_launch(void* const* d_in, const int* in_sizes, int n_in,
                              void* d_out, int out_size, void* d_ws, size_t ws_size,
                              hipStream_t stream) {
  const float* x    = (const float*)d_in[0];
  const float* w    = (const float*)d_in[1];
  const float* bias = (const float*)d_in[2];
  const int*   sp   = (const int*)d_in[3];
  const int*   dr   = (const int*)d_in[4];
  const int*   dc   = (const int*)d_in[5];
  const float* dd   = (const float*)d_in[6];
  float* out = (float*)d_out;

  char* ws = (char*)d_ws;
  unsigned short* wfr = (unsigned short*)ws;        // 147456 B (frag-major W)
  unsigned short* xbf = (unsigned short*)(ws + 147456);     // 51200000 B
  unsigned short* hbf = (unsigned short*)(ws + 51347456);   // 102400000 B worst case
  int*  cursor  = (int*) (ws + 153747456);          // 50000 B (memset with used+Ucnt)
  int*  used    = (int*) (ws + 153797456);          // 200000 B
  int*  Ucnt    = (int*) (ws + 153997456);          // 16 B
  int2* elist   = (int2*)(ws + 153997472);          // 3200000 B
  int*  rmap    = (int*) (ws + 157197472);          // 200000 B
  int*  cidx    = (int*) (ws + 157397472);          // 200000 B

  (void)hipMemsetAsync(cursor, 0, 250016, stream);  // cursor + used + Ucnt
  prep<<<PREP_WBLK + PREP_FBLK + PREP_XBLK, 256, 0, stream>>>(
      w, wfr, x, xbf, dr, dc, dd, cursor, used, Ucnt, elist, rmap, cidx);
  spiral_gemm<<<NWG, 256, 0, stream>>>(xbf, wfr, bias, sp, rmap, Ucnt, hbf);
  pool_rows<<<VOUT_, 256, 0, stream>>>(hbf, cursor, elist, cidx, Ucnt, out);
}